// Round 7
// baseline (731.727 us; speedup 1.0000x reference)
//
#include <hip/hip_runtime.h>
#include <hip/hip_bf16.h>
#include <cstddef>
#include <cstdint>

#define NBLK(n, b) (((n) + (b) - 1) / (b))

typedef __attribute__((ext_vector_type(8))) short short8;
typedef __attribute__((ext_vector_type(4))) float f32x4;

__device__ inline unsigned short f2bf(float f) {
  union { float f; unsigned u; } v; v.f = f;
  unsigned u = v.u;
  u += 0x7FFFu + ((u >> 16) & 1u);  // RNE
  return (unsigned short)(u >> 16);
}
__device__ inline float bflo(unsigned u) { union { unsigned u; float f; } v; v.u = u << 16; return v.f; }
__device__ inline float bfhi(unsigned u) { union { unsigned u; float f; } v; v.u = u & 0xFFFF0000u; return v.f; }

// unpack 8 bf16 (one uint4) and accumulate into 8 f32 (static indices only)
__device__ inline void add8(float* a, uint4 v) {
  a[0] += bflo(v.x); a[1] += bfhi(v.x);
  a[2] += bflo(v.y); a[3] += bfhi(v.y);
  a[4] += bflo(v.z); a[5] += bfhi(v.z);
  a[6] += bflo(v.w); a[7] += bfhi(v.w);
}

// DEAD END (R3-R5): LDS-atomic accumulation — divergent-lane LDS atomics
// serialize in the RMW unit (~1.2 ms). Do not revisit.
// DEAD END (R2/R6): wave-cooperative gather per node-slice — per-node-slice
// fixed cost (shfl reduce + pack) x 800K node-slices = ~22M wave-instrs,
// 3.5x the useful work. Hence: one lane = one node-slice, degree-sorted.

// CSR bucket sort: buckets of 512 nodes; node ids < 2^17 (N=100K).
// key = src | (localDst << 17) fits u32. Fixed-capacity padded buckets.
#define BSHIFT 9
#define BSIZE 512
#define CAPSHIFT 14
#define CAP 16384
#define ECHUNK 2048

// All bf16 feature tensors live in SLICE-TRANSPOSED layout:
//   element (node, ch) at half-index ((ch>>4) * N + node) * 16 + (ch & 15)
// i.e. T[g][N][16ch], 32 B per node per 16-ch slice; slice = 3.2 MB -> fits an
// XCD's 4 MB L2; aggregation uses slice = blockIdx.x & 7 (XCD-affine via %8
// round-robin). Confirmed R1-R6: FETCH at compulsory (~44 MB).

// ---------------- cast x -> bf16 sliced layout, prep packed weights ----------------
__global__ __launch_bounds__(256) void k_cast(
    const float* __restrict__ x, unsigned* __restrict__ xT, int N,
    const float* __restrict__ W1l, const float* __restrict__ W1r, unsigned short* __restrict__ Wb1,
    const float* __restrict__ W2l, const float* __restrict__ W2r, unsigned short* __restrict__ Wb2,
    const float* __restrict__ W3l, const float* __restrict__ W3r, unsigned short* __restrict__ Wb3) {
  int t = threadIdx.x;
  int b = blockIdx.x;
  int gCast = (N * 64 + 255) >> 8;
  if (b < gCast) {
    int i = b * 256 + t;
    if (i < N * 64) {
      float2 v = *(const float2*)(x + (size_t)i * 2);
      int node = i >> 6, j = i & 63;
      xT[((size_t)(j >> 3) * N + node) * 8 + (j & 7)] =
          (unsigned)f2bf(v.x) | ((unsigned)f2bf(v.y) << 16);
    }
    return;
  }
  b -= gCast;
  int ii = b * 256 + t;
  const float *Wl, *Wr; unsigned short* Wb;
  if (ii < 128 * 256) { Wl = W1l; Wr = W1r; Wb = Wb1; }
  else if (ii < 256 * 256) { Wl = W2l; Wr = W2r; Wb = Wb2; ii -= 128 * 256; }
  else { Wl = W3l; Wr = W3r; Wb = Wb3; ii -= 256 * 256; }
  int nrow = ii >> 8, k = ii & 255;
  float v = (k < 128) ? Wr[nrow * 128 + k] : Wl[nrow * 128 + (k - 128)];
  Wb[ii] = f2bf(v);
}

// ---------------- edge scatter into padded buckets ----------------
__global__ __launch_bounds__(256) void k_scatter(
    const void* __restrict__ edges, int* __restrict__ bucketCursor,
    unsigned* __restrict__ bucketed, int E, int NB) {
  __shared__ int h[1024];
  __shared__ int base2[1024];
  int t = threadIdx.x;
  int b = blockIdx.x;

  const unsigned* e32 = (const unsigned*)edges;
  int is64 = 1;
#pragma unroll
  for (int i = 0; i < 16; ++i)
    if (e32[2 * i + 1] != 0u) is64 = 0;

  for (int i = t; i < NB; i += 256) h[i] = 0;
  __syncthreads();
  int base_e = b * ECHUNK;
  unsigned key[8];
  int bkt[8];
#pragma unroll
  for (int k = 0; k < 8; ++k) {
    int e = base_e + k * 256 + t;
    bkt[k] = -1;
    if (e < E) {
      int s, d;
      if (is64) {
        s = (int)((const long long*)edges)[e];
        d = (int)((const long long*)edges)[(size_t)E + e];
      } else {
        s = ((const int*)edges)[e];
        d = ((const int*)edges)[(size_t)E + e];
      }
      bkt[k] = d >> BSHIFT;
      key[k] = (unsigned)s | ((unsigned)(d & (BSIZE - 1)) << 17);
      atomicAdd(&h[bkt[k]], 1);
    }
  }
  __syncthreads();
  for (int i = t; i < NB; i += 256) {
    int c = h[i];
    base2[i] = c ? atomicAdd(&bucketCursor[i], c) : 0;
    h[i] = 0;
  }
  __syncthreads();
#pragma unroll
  for (int k = 0; k < 8; ++k) {
    if (bkt[k] >= 0) {
      int r = atomicAdd(&h[bkt[k]], 1);
      int pos = base2[bkt[k]] + r;
      if (pos < CAP)
        bucketed[((size_t)bkt[k] << CAPSHIFT) + pos] = key[k];
    }
  }
}

// ---------------- per-bucket CSR + in-bucket degree sort ----------------
// Produces rowStart/deg/srcSorted AND perm: nodes of each bucket reordered by
// ascending (clamped) degree, so each aggregation wave's 64 lanes get
// near-equal degree (kills max/mean divergence waste).
__global__ __launch_bounds__(256) void k_csr(const unsigned* __restrict__ bucketed,
                                             const int* __restrict__ bucketCursor,
                                             int* __restrict__ rowStart, int* __restrict__ deg,
                                             int* __restrict__ srcSorted, int* __restrict__ perm,
                                             int N, int NB) {
  __shared__ int h[512];
  __shared__ int excl[512];
  __shared__ int sd[256];
  int b = blockIdx.x;
  int t = threadIdx.x;
  int nodeBase = b << BSHIFT;
  int nNode = min(BSIZE, N - nodeBase);
  int cnt = min(bucketCursor[b], CAP);
  size_t s0 = (size_t)b << CAPSHIFT;
  h[t * 2] = 0; h[t * 2 + 1] = 0;
  __syncthreads();
  for (int i = t; i < cnt; i += 256) {
    int ld = bucketed[s0 + i] >> 17;
    atomicAdd(&h[ld], 1);
  }
  __syncthreads();
  int a0 = h[t * 2], a1 = h[t * 2 + 1];
  int s = a0 + a1;
  sd[t] = s;
  __syncthreads();
  for (int off = 1; off < 256; off <<= 1) {
    int xv = (t >= off) ? sd[t - off] : 0;
    __syncthreads();
    sd[t] += xv;
    __syncthreads();
  }
  int run = sd[t] - s;
  excl[t * 2] = run;
  excl[t * 2 + 1] = run + a0;
  if (t * 2 < nNode) {
    rowStart[nodeBase + t * 2] = (int)s0 + run;
    deg[nodeBase + t * 2] = a0;
  }
  if (t * 2 + 1 < nNode) {
    rowStart[nodeBase + t * 2 + 1] = (int)s0 + run + a0;
    deg[nodeBase + t * 2 + 1] = a1;
  }
  h[t * 2] = 0; h[t * 2 + 1] = 0;
  __syncthreads();
  for (int i = t; i < cnt; i += 256) {
    unsigned u = bucketed[s0 + i];
    int ld = u >> 17;
    int r = atomicAdd(&h[ld], 1);
    srcSorted[s0 + excl[ld] + r] = (int)(u & 0x1FFFFu);
  }
  // ---- in-bucket counting sort by degree (64 bins, clamp) -> perm ----
  __syncthreads();
  if (t < 64) sd[t] = 0;
  __syncthreads();
  if (t * 2 < nNode) atomicAdd(&sd[min(a0, 63)], 1);
  if (t * 2 + 1 < nNode) atomicAdd(&sd[min(a1, 63)], 1);
  __syncthreads();
  if (t == 0) {
    int r2 = 0;
    for (int i = 0; i < 64; ++i) { int c = sd[i]; excl[i] = r2; r2 += c; }
  }
  __syncthreads();
  if (t * 2 < nNode) {
    int p = atomicAdd(&excl[min(a0, 63)], 1);
    perm[nodeBase + p] = nodeBase + t * 2;
  }
  if (t * 2 + 1 < nNode) {
    int p = atomicAdd(&excl[min(a1, 63)], 1);
    perm[nodeBase + p] = nodeBase + t * 2 + 1;
  }
}

// ---------------- per-lane-node slice aggregation (128-ch layers) ----------------
// grid.x = 8 * ceil(N/256); slice g = bid & 7 (XCD-affine). One lane owns one
// (node, 16-ch slice): acc[16] in registers, serial degree-sorted edge walk,
// unroll-2 (6 loads in flight). No reduction, no LDS; pack+store per lane.
__global__ __launch_bounds__(256) void k_agg_slice(
    const uint4* __restrict__ inT, const int* __restrict__ rowStart,
    const int* __restrict__ deg, const int* __restrict__ srcs,
    const int* __restrict__ perm, uint4* __restrict__ outT, int n) {
  int g = blockIdx.x & 7;
  int idx = (blockIdx.x >> 3) * 256 + threadIdx.x;
  if (idx >= n) return;
  int node = perm[idx];
  int r0 = rowStart[node];
  int dg = deg[node];
  const uint4* bp = inT + (size_t)g * n * 2;
  float acc[16];
#pragma unroll
  for (int k = 0; k < 16; ++k) acc[k] = 0.f;

  int e = 0;
  for (; e + 2 <= dg; e += 2) {
    int s0 = srcs[r0 + e];
    int s1 = srcs[r0 + e + 1];
    uint4 a0 = bp[(size_t)s0 * 2];
    uint4 a1 = bp[(size_t)s0 * 2 + 1];
    uint4 b0 = bp[(size_t)s1 * 2];
    uint4 b1 = bp[(size_t)s1 * 2 + 1];
    add8(acc, a0); add8(acc + 8, a1);
    add8(acc, b0); add8(acc + 8, b1);
  }
  if (e < dg) {
    int s0 = srcs[r0 + e];
    uint4 a0 = bp[(size_t)s0 * 2];
    uint4 a1 = bp[(size_t)s0 * 2 + 1];
    add8(acc, a0); add8(acc + 8, a1);
  }

  float sc = 1.0f / (float)max(dg, 1);
  uint4 o0, o1;
  o0.x = (unsigned)f2bf(acc[0] * sc) | ((unsigned)f2bf(acc[1] * sc) << 16);
  o0.y = (unsigned)f2bf(acc[2] * sc) | ((unsigned)f2bf(acc[3] * sc) << 16);
  o0.z = (unsigned)f2bf(acc[4] * sc) | ((unsigned)f2bf(acc[5] * sc) << 16);
  o0.w = (unsigned)f2bf(acc[6] * sc) | ((unsigned)f2bf(acc[7] * sc) << 16);
  o1.x = (unsigned)f2bf(acc[8] * sc) | ((unsigned)f2bf(acc[9] * sc) << 16);
  o1.y = (unsigned)f2bf(acc[10] * sc) | ((unsigned)f2bf(acc[11] * sc) << 16);
  o1.z = (unsigned)f2bf(acc[12] * sc) | ((unsigned)f2bf(acc[13] * sc) << 16);
  o1.w = (unsigned)f2bf(acc[14] * sc) | ((unsigned)f2bf(acc[15] * sc) << 16);
  outT[((size_t)g * n + node) * 2] = o0;
  outT[((size_t)g * n + node) * 2 + 1] = o1;
}

// ---------------- layer-3 per-lane-node aggregate: out += mean(y3) ----------------
// grid.x = 4 * ceil(N/256); slice g = bid & 3 (y3 is 64-ch = 4 slices).
__global__ __launch_bounds__(256) void k_agg64_slice(
    const uint4* __restrict__ y3T, const int* __restrict__ rowStart,
    const int* __restrict__ deg, const int* __restrict__ srcs,
    const int* __restrict__ perm, float* __restrict__ outp, int n) {
  int g = blockIdx.x & 3;
  int idx = (blockIdx.x >> 2) * 256 + threadIdx.x;
  if (idx >= n) return;
  int node = perm[idx];
  int dg = deg[node];
  if (dg == 0) return;
  int r0 = rowStart[node];
  const uint4* bp = y3T + (size_t)g * n * 2;
  float acc[16];
#pragma unroll
  for (int k = 0; k < 16; ++k) acc[k] = 0.f;

  int e = 0;
  for (; e + 2 <= dg; e += 2) {
    int s0 = srcs[r0 + e];
    int s1 = srcs[r0 + e + 1];
    uint4 a0 = bp[(size_t)s0 * 2];
    uint4 a1 = bp[(size_t)s0 * 2 + 1];
    uint4 b0 = bp[(size_t)s1 * 2];
    uint4 b1 = bp[(size_t)s1 * 2 + 1];
    add8(acc, a0); add8(acc + 8, a1);
    add8(acc, b0); add8(acc + 8, b1);
  }
  if (e < dg) {
    int s0 = srcs[r0 + e];
    uint4 a0 = bp[(size_t)s0 * 2];
    uint4 a1 = bp[(size_t)s0 * 2 + 1];
    add8(acc, a0); add8(acc + 8, a1);
  }

  float sc = 1.0f / (float)dg;
  float* op = outp + (size_t)node * 64 + g * 16;
  float4 v0 = *(float4*)op;
  float4 v1 = *(float4*)(op + 4);
  float4 v2 = *(float4*)(op + 8);
  float4 v3 = *(float4*)(op + 12);
  v0.x += acc[0] * sc; v0.y += acc[1] * sc; v0.z += acc[2] * sc; v0.w += acc[3] * sc;
  v1.x += acc[4] * sc; v1.y += acc[5] * sc; v1.z += acc[6] * sc; v1.w += acc[7] * sc;
  v2.x += acc[8] * sc; v2.y += acc[9] * sc; v2.z += acc[10] * sc; v2.w += acc[11] * sc;
  v3.x += acc[12] * sc; v3.y += acc[13] * sc; v3.z += acc[14] * sc; v3.w += acc[15] * sc;
  *(float4*)op = v0;
  *(float4*)(op + 4) = v1;
  *(float4*)(op + 8) = v2;
  *(float4*)(op + 12) = v3;
}

// ---------------- MFMA GEMM: out = self@Wr.T + mean@Wl.T + b (layers 1-2) ----------------
template <int H, bool RELU>
__global__ __launch_bounds__(256) void k_gemm(
    const unsigned short* __restrict__ selfT, const unsigned short* __restrict__ meanT,
    const unsigned short* __restrict__ Wb, const float* __restrict__ bias,
    unsigned short* __restrict__ outT, int n) {
  constexpr int TN = H / 32;
  int lane = threadIdx.x & 63;
  int w = threadIdx.x >> 6;
  int wr = w & 1, wc = w >> 1;
  int nodeBase = blockIdx.x * 128 + wr * 64;
  int colBase = wc * (H / 2);
  int l15 = lane & 15, quad = lane >> 4;

  f32x4 acc[4][TN];
#pragma unroll
  for (int t = 0; t < 4; ++t)
#pragma unroll
    for (int j = 0; j < TN; ++j) acc[t][j] = (f32x4){0.f, 0.f, 0.f, 0.f};

#pragma unroll
  for (int c = 0; c < 8; ++c) {
    const unsigned short* A = (c < 4) ? selfT : meanT;
    int ko = (c & 3) * 32 + quad * 8;
    int gk = ko >> 4;
    int wo = ko & 15;
    short8 af[4], bfr[TN];
#pragma unroll
    for (int t = 0; t < 4; ++t) {
      int row = min(nodeBase + t * 16 + l15, n - 1);
      af[t] = *(const short8*)(A + ((size_t)gk * n + row) * 16 + wo);
    }
#pragma unroll
    for (int j = 0; j < TN; ++j) {
      int cn = colBase + j * 16 + l15;
      bfr[j] = *(const short8*)(Wb + (size_t)cn * 256 + c * 32 + quad * 8);
    }
#pragma unroll
    for (int t = 0; t < 4; ++t)
#pragma unroll
      for (int j = 0; j < TN; ++j)
        acc[t][j] = __builtin_amdgcn_mfma_f32_16x16x32_bf16(af[t], bfr[j], acc[t][j], 0, 0, 0);
  }

#pragma unroll
  for (int j = 0; j < TN; ++j) {
    int col = colBase + j * 16 + l15;
    int gc = col >> 4;
    float bv = bias[col];
#pragma unroll
    for (int t = 0; t < 4; ++t) {
#pragma unroll
      for (int r = 0; r < 4; ++r) {
        int row = nodeBase + t * 16 + quad * 4 + r;
        if (row < n) {
          float v = acc[t][j][r] + bv;
          if (RELU) v = fmaxf(v, 0.f);
          outT[((size_t)gc * n + row) * 16 + l15] = f2bf(v);
        }
      }
    }
  }
}

// ---------------- layer-3 combined transform ----------------
__global__ __launch_bounds__(256) void k_gemm3_both(
    const unsigned short* __restrict__ A,
    const unsigned short* __restrict__ Wb3,
    const float* __restrict__ bias,
    float* __restrict__ outp, unsigned short* __restrict__ y3T, int n) {
  int lane = threadIdx.x & 63;
  int w = threadIdx.x >> 6;
  int wr = w & 1, wc = w >> 1;
  int nodeBase = blockIdx.x * 128 + wr * 64;
  int l15 = lane & 15, quad = lane >> 4;
  int woff = wc ? 128 : 0;
  f32x4 acc[4][4];
#pragma unroll
  for (int t = 0; t < 4; ++t)
#pragma unroll
    for (int j = 0; j < 4; ++j) acc[t][j] = (f32x4){0.f, 0.f, 0.f, 0.f};
#pragma unroll
  for (int c = 0; c < 4; ++c) {
    int ko = c * 32 + quad * 8;
    int gk = ko >> 4;
    int wo = ko & 15;
    short8 af[4], bfr[4];
#pragma unroll
    for (int t = 0; t < 4; ++t) {
      int row = min(nodeBase + t * 16 + l15, n - 1);
      af[t] = *(const short8*)(A + ((size_t)gk * n + row) * 16 + wo);
    }
#pragma unroll
    for (int j = 0; j < 4; ++j) {
      int cn = j * 16 + l15;
      bfr[j] = *(const short8*)(Wb3 + (size_t)cn * 256 + woff + c * 32 + quad * 8);
    }
#pragma unroll
    for (int t = 0; t < 4; ++t)
#pragma unroll
      for (int j = 0; j < 4; ++j)
        acc[t][j] = __builtin_amdgcn_mfma_f32_16x16x32_bf16(af[t], bfr[j], acc[t][j], 0, 0, 0);
  }
#pragma unroll
  for (int j = 0; j < 4; ++j) {
    int col = j * 16 + l15;
    float bv = wc ? 0.f : bias[col];
#pragma unroll
    for (int t = 0; t < 4; ++t) {
#pragma unroll
      for (int r = 0; r < 4; ++r) {
        int row = nodeBase + t * 16 + quad * 4 + r;
        if (row < n) {
          float v = acc[t][j][r] + bv;
          if (wc) y3T[((size_t)j * n + row) * 16 + l15] = f2bf(v);
          else outp[(size_t)row * 64 + col] = v;
        }
      }
    }
  }
}

// ---------------- launch ----------------

extern "C" void kernel_launch(void* const* d_in, const int* in_sizes, int n_in,
                              void* d_out, int out_size, void* d_ws, size_t ws_size,
                              hipStream_t stream) {
  (void)n_in; (void)out_size; (void)ws_size;
  const float* x = (const float*)d_in[0];
  const void* edges = d_in[1];
  const float* W1l = (const float*)d_in[2];
  const float* W1r = (const float*)d_in[3];
  const float* b1 = (const float*)d_in[4];
  const float* W2l = (const float*)d_in[5];
  const float* W2r = (const float*)d_in[6];
  const float* b2 = (const float*)d_in[7];
  const float* W3l = (const float*)d_in[8];
  const float* W3r = (const float*)d_in[9];
  const float* b3 = (const float*)d_in[10];
  float* out = (float*)d_out;

  const int N = in_sizes[0] / 128;
  const int E = in_sizes[1] / 2;
  const int NB = (N + BSIZE - 1) >> BSHIFT;

  char* ws = (char*)d_ws;
  size_t off = 0;
  auto alloc = [&](size_t bytes) -> char* {
    char* p = ws + off;
    off = (off + bytes + 255) & ~(size_t)255;
    return p;
  };
  int* bucketCursor = (int*)alloc((size_t)NB * 4);
  unsigned* bucketed = (unsigned*)alloc((size_t)NB * CAP * 4);
  int* rowStart = (int*)alloc((size_t)N * 4);
  int* deg = (int*)alloc((size_t)N * 4);
  int* perm = (int*)alloc((size_t)N * 4);
  int* srcSorted = (int*)alloc((size_t)NB * CAP * 4);
  unsigned short* xT = (unsigned short*)alloc((size_t)N * 128 * 2);
  unsigned short* meanT = (unsigned short*)alloc((size_t)N * 128 * 2);
  unsigned short* h1T = (unsigned short*)alloc((size_t)N * 128 * 2);
  unsigned short* h2T = (unsigned short*)alloc((size_t)N * 128 * 2);
  unsigned short* y3T = (unsigned short*)alloc((size_t)N * 64 * 2);
  unsigned short* Wb1 = (unsigned short*)alloc(128 * 256 * 2);
  unsigned short* Wb2 = (unsigned short*)alloc(128 * 256 * 2);
  unsigned short* Wb3 = (unsigned short*)alloc(64 * 256 * 2);

  int gCast = NBLK(N * 64, 256) + 320;
  int gE = NBLK(E, ECHUNK);
  int gAgg = NBLK(N, 256) * 8;
  int gAgg64 = NBLK(N, 256) * 4;
  int gGemm = NBLK(N, 128);

  hipMemsetAsync(bucketCursor, 0, (size_t)NB * 4, stream);
  k_cast<<<gCast, 256, 0, stream>>>(x, (unsigned*)xT, N,
                                    W1l, W1r, Wb1, W2l, W2r, Wb2, W3l, W3r, Wb3);
  k_scatter<<<gE, 256, 0, stream>>>(edges, bucketCursor, bucketed, E, NB);
  k_csr<<<NB, 256, 0, stream>>>(bucketed, bucketCursor, rowStart, deg, srcSorted, perm, N, NB);

  // layer 1
  k_agg_slice<<<gAgg, 256, 0, stream>>>((const uint4*)xT, rowStart, deg, srcSorted, perm,
                                        (uint4*)meanT, N);
  k_gemm<128, true><<<gGemm, 256, 0, stream>>>(xT, meanT, Wb1, b1, h1T, N);
  // layer 2
  k_agg_slice<<<gAgg, 256, 0, stream>>>((const uint4*)h1T, rowStart, deg, srcSorted, perm,
                                        (uint4*)meanT, N);
  k_gemm<128, true><<<gGemm, 256, 0, stream>>>(h1T, meanT, Wb2, b2, h2T, N);
  // layer 3: transform-first
  k_gemm3_both<<<gGemm, 256, 0, stream>>>(h2T, Wb3, b3, out, y3T, N);
  k_agg64_slice<<<gAgg64, 256, 0, stream>>>((const uint4*)y3T, rowStart, deg, srcSorted, perm,
                                            out, N);
}

// Round 8
// 478.827 us; speedup vs baseline: 1.5282x; 1.5282x over previous
//
#include <hip/hip_runtime.h>
#include <hip/hip_bf16.h>
#include <cstddef>
#include <cstdint>

#define NBLK(n, b) (((n) + (b) - 1) / (b))

typedef __attribute__((ext_vector_type(8))) short short8;
typedef __attribute__((ext_vector_type(4))) float f32x4;

__device__ inline unsigned short f2bf(float f) {
  union { float f; unsigned u; } v; v.f = f;
  unsigned u = v.u;
  u += 0x7FFFu + ((u >> 16) & 1u);  // RNE
  return (unsigned short)(u >> 16);
}
__device__ inline float bflo(unsigned u) { union { unsigned u; float f; } v; v.u = u << 16; return v.f; }
__device__ inline float bfhi(unsigned u) { union { unsigned u; float f; } v; v.u = u & 0xFFFF0000u; return v.f; }

// unpack 8 bf16 (one uint4) and accumulate into 8 f32 (static indices only)
__device__ inline void add8(float* a, uint4 v) {
  a[0] += bflo(v.x); a[1] += bfhi(v.x);
  a[2] += bflo(v.y); a[3] += bfhi(v.y);
  a[4] += bflo(v.z); a[5] += bfhi(v.z);
  a[6] += bflo(v.w); a[7] += bfhi(v.w);
}

// DEAD END (R3-R5): LDS-atomic accumulation — divergent-lane LDS atomics
// serialize in the RMW unit (~1.2 ms). Do not revisit.
// DEAD END (R1/R2/R6): channel-sliced layouts — traffic drops to compulsory
// (44 MB) but the 8x edge-walk overhead costs ~60us VALU in every variant.
// DEAD END (R7): per-lane-node serial walk — L2 thrash (FETCH 390 MB) +
// latency-bound at 6 loads/lane. Row-major wave-cooperative (R0) is the
// measured optimum family; this round doubles its memory-level parallelism.

// CSR bucket sort: buckets of 512 nodes; node ids < 2^17 (N=100K).
// key = src | (localDst << 17) fits u32. Fixed-capacity padded buckets.
#define BSHIFT 9
#define BSIZE 512
#define CAPSHIFT 14
#define CAP 16384
#define ECHUNK 2048

// ---------------- cast x -> bf16 (row-major 256B rows), prep packed weights ----------------
__global__ __launch_bounds__(256) void k_cast(
    const float* __restrict__ x, unsigned* __restrict__ xb, int N,
    const float* __restrict__ W1l, const float* __restrict__ W1r, unsigned short* __restrict__ Wb1,
    const float* __restrict__ W2l, const float* __restrict__ W2r, unsigned short* __restrict__ Wb2,
    const float* __restrict__ W3l, const float* __restrict__ W3r, unsigned short* __restrict__ Wb3) {
  int t = threadIdx.x;
  int b = blockIdx.x;
  int gCast = (N * 64 + 255) >> 8;
  if (b < gCast) {
    int i = b * 256 + t;
    if (i < N * 64) {
      float2 v = *(const float2*)(x + (size_t)i * 2);
      xb[i] = (unsigned)f2bf(v.x) | ((unsigned)f2bf(v.y) << 16);
    }
    return;
  }
  b -= gCast;
  int ii = b * 256 + t;
  const float *Wl, *Wr; unsigned short* Wb;
  if (ii < 128 * 256) { Wl = W1l; Wr = W1r; Wb = Wb1; }
  else if (ii < 256 * 256) { Wl = W2l; Wr = W2r; Wb = Wb2; ii -= 128 * 256; }
  else { Wl = W3l; Wr = W3r; Wb = Wb3; ii -= 256 * 256; }
  int nrow = ii >> 8, k = ii & 255;
  float v = (k < 128) ? Wr[nrow * 128 + k] : Wl[nrow * 128 + (k - 128)];
  Wb[ii] = f2bf(v);
}

// ---------------- edge scatter into padded buckets ----------------
__global__ __launch_bounds__(256) void k_scatter(
    const void* __restrict__ edges, int* __restrict__ bucketCursor,
    unsigned* __restrict__ bucketed, int E, int NB) {
  __shared__ int h[1024];
  __shared__ int base2[1024];
  int t = threadIdx.x;
  int b = blockIdx.x;

  const unsigned* e32 = (const unsigned*)edges;
  int is64 = 1;
#pragma unroll
  for (int i = 0; i < 16; ++i)
    if (e32[2 * i + 1] != 0u) is64 = 0;

  for (int i = t; i < NB; i += 256) h[i] = 0;
  __syncthreads();
  int base_e = b * ECHUNK;
  unsigned key[8];
  int bkt[8];
#pragma unroll
  for (int k = 0; k < 8; ++k) {
    int e = base_e + k * 256 + t;
    bkt[k] = -1;
    if (e < E) {
      int s, d;
      if (is64) {
        s = (int)((const long long*)edges)[e];
        d = (int)((const long long*)edges)[(size_t)E + e];
      } else {
        s = ((const int*)edges)[e];
        d = ((const int*)edges)[(size_t)E + e];
      }
      bkt[k] = d >> BSHIFT;
      key[k] = (unsigned)s | ((unsigned)(d & (BSIZE - 1)) << 17);
      atomicAdd(&h[bkt[k]], 1);
    }
  }
  __syncthreads();
  for (int i = t; i < NB; i += 256) {
    int c = h[i];
    base2[i] = c ? atomicAdd(&bucketCursor[i], c) : 0;
    h[i] = 0;
  }
  __syncthreads();
#pragma unroll
  for (int k = 0; k < 8; ++k) {
    if (bkt[k] >= 0) {
      int r = atomicAdd(&h[bkt[k]], 1);
      int pos = base2[bkt[k]] + r;
      if (pos < CAP)
        bucketed[((size_t)bkt[k] << CAPSHIFT) + pos] = key[k];
    }
  }
}

// ---------------- per-bucket CSR + in-bucket degree sort ----------------
// rowStart/deg/srcSorted as R0, plus perm: nodes of each bucket reordered by
// ascending (clamped) degree so paired nodes per wave have near-equal degree.
__global__ __launch_bounds__(256) void k_csr(const unsigned* __restrict__ bucketed,
                                             const int* __restrict__ bucketCursor,
                                             int* __restrict__ rowStart, int* __restrict__ deg,
                                             int* __restrict__ srcSorted, int* __restrict__ perm,
                                             int N, int NB) {
  __shared__ int h[512];
  __shared__ int excl[512];
  __shared__ int sd[256];
  int b = blockIdx.x;
  int t = threadIdx.x;
  int nodeBase = b << BSHIFT;
  int nNode = min(BSIZE, N - nodeBase);
  int cnt = min(bucketCursor[b], CAP);
  size_t s0 = (size_t)b << CAPSHIFT;
  h[t * 2] = 0; h[t * 2 + 1] = 0;
  __syncthreads();
  for (int i = t; i < cnt; i += 256) {
    int ld = bucketed[s0 + i] >> 17;
    atomicAdd(&h[ld], 1);
  }
  __syncthreads();
  int a0 = h[t * 2], a1 = h[t * 2 + 1];
  int s = a0 + a1;
  sd[t] = s;
  __syncthreads();
  for (int off = 1; off < 256; off <<= 1) {
    int xv = (t >= off) ? sd[t - off] : 0;
    __syncthreads();
    sd[t] += xv;
    __syncthreads();
  }
  int run = sd[t] - s;
  excl[t * 2] = run;
  excl[t * 2 + 1] = run + a0;
  if (t * 2 < nNode) {
    rowStart[nodeBase + t * 2] = (int)s0 + run;
    deg[nodeBase + t * 2] = a0;
  }
  if (t * 2 + 1 < nNode) {
    rowStart[nodeBase + t * 2 + 1] = (int)s0 + run + a0;
    deg[nodeBase + t * 2 + 1] = a1;
  }
  h[t * 2] = 0; h[t * 2 + 1] = 0;
  __syncthreads();
  for (int i = t; i < cnt; i += 256) {
    unsigned u = bucketed[s0 + i];
    int ld = u >> 17;
    int r = atomicAdd(&h[ld], 1);
    srcSorted[s0 + excl[ld] + r] = (int)(u & 0x1FFFFu);
  }
  // ---- in-bucket counting sort by degree (64 bins, clamp) -> perm ----
  __syncthreads();
  if (t < 64) sd[t] = 0;
  __syncthreads();
  if (t * 2 < nNode) atomicAdd(&sd[min(a0, 63)], 1);
  if (t * 2 + 1 < nNode) atomicAdd(&sd[min(a1, 63)], 1);
  __syncthreads();
  if (t == 0) {
    int r2 = 0;
    for (int i = 0; i < 64; ++i) { int c = sd[i]; excl[i] = r2; r2 += c; }
  }
  __syncthreads();
  if (t * 2 < nNode) {
    int p = atomicAdd(&excl[min(a0, 63)], 1);
    perm[nodeBase + p] = nodeBase + t * 2;
  }
  if (t * 2 + 1 < nNode) {
    int p = atomicAdd(&excl[min(a1, 63)], 1);
    perm[nodeBase + p] = nodeBase + t * 2 + 1;
  }
}

// ---------------- aggregation: mean over in-neighbors, 256B rows (bf16) ----------------
// R0 structure + 2 nodes per wave (degree-matched via perm) => 8 gathers in
// flight per lane in the main tier (was 4). Lane = (eg in [0,4)) x (sub in [0,16)).
__global__ void k_aggregate(const unsigned* __restrict__ in, const int* __restrict__ rowStart,
                            const int* __restrict__ deg, const int* __restrict__ srcs,
                            const int* __restrict__ perm, unsigned* __restrict__ mean, int n) {
  int lane = threadIdx.x & 63;
  int w = threadIdx.x >> 6;
  int i0 = blockIdx.x * 8 + w * 2;
  bool vA = i0 < n, vB = i0 + 1 < n;
  int nA = vA ? perm[i0] : 0;
  int nB = vB ? perm[i0 + 1] : 0;
  int dga = vA ? deg[nA] : 0;
  int dgb = vB ? deg[nB] : 0;
  int r0a = vA ? rowStart[nA] : 0;
  int r0b = vB ? rowStart[nB] : 0;
  int sub = lane & 15;
  int eg = lane >> 4;
  float accA[8], accB[8];
#pragma unroll
  for (int k = 0; k < 8; ++k) { accA[k] = 0.f; accB[k] = 0.f; }

  int mx = max(dga, dgb);
  for (int base = 0; base < mx; base += 64) {
    int cA = min(64, dga - base);
    int cB = min(64, dgb - base);
    int svA = (lane < cA) ? srcs[r0a + base + lane] : 0;
    int svB = (lane < cB) ? srcs[r0b + base + lane] : 0;
    int j = 0;
    int cM = min(cA, cB);
    for (; j + 16 <= cM; j += 16) {
      int a0 = __shfl(svA, j + eg), a1 = __shfl(svA, j + 4 + eg);
      int a2 = __shfl(svA, j + 8 + eg), a3 = __shfl(svA, j + 12 + eg);
      int b0 = __shfl(svB, j + eg), b1 = __shfl(svB, j + 4 + eg);
      int b2 = __shfl(svB, j + 8 + eg), b3 = __shfl(svB, j + 12 + eg);
      uint4 uA0 = *(const uint4*)(in + (size_t)a0 * 64 + sub * 4);
      uint4 uA1 = *(const uint4*)(in + (size_t)a1 * 64 + sub * 4);
      uint4 uA2 = *(const uint4*)(in + (size_t)a2 * 64 + sub * 4);
      uint4 uA3 = *(const uint4*)(in + (size_t)a3 * 64 + sub * 4);
      uint4 uB0 = *(const uint4*)(in + (size_t)b0 * 64 + sub * 4);
      uint4 uB1 = *(const uint4*)(in + (size_t)b1 * 64 + sub * 4);
      uint4 uB2 = *(const uint4*)(in + (size_t)b2 * 64 + sub * 4);
      uint4 uB3 = *(const uint4*)(in + (size_t)b3 * 64 + sub * 4);
      add8(accA, uA0); add8(accA, uA1); add8(accA, uA2); add8(accA, uA3);
      add8(accB, uB0); add8(accB, uB1); add8(accB, uB2); add8(accB, uB3);
    }
    // finish A
    int ja = j;
    for (; ja + 16 <= cA; ja += 16) {
      int a0 = __shfl(svA, ja + eg), a1 = __shfl(svA, ja + 4 + eg);
      int a2 = __shfl(svA, ja + 8 + eg), a3 = __shfl(svA, ja + 12 + eg);
      uint4 u0 = *(const uint4*)(in + (size_t)a0 * 64 + sub * 4);
      uint4 u1 = *(const uint4*)(in + (size_t)a1 * 64 + sub * 4);
      uint4 u2 = *(const uint4*)(in + (size_t)a2 * 64 + sub * 4);
      uint4 u3 = *(const uint4*)(in + (size_t)a3 * 64 + sub * 4);
      add8(accA, u0); add8(accA, u1); add8(accA, u2); add8(accA, u3);
    }
    for (; ja + 8 <= cA; ja += 8) {
      int a0 = __shfl(svA, ja + eg), a1 = __shfl(svA, ja + 4 + eg);
      uint4 u0 = *(const uint4*)(in + (size_t)a0 * 64 + sub * 4);
      uint4 u1 = *(const uint4*)(in + (size_t)a1 * 64 + sub * 4);
      add8(accA, u0); add8(accA, u1);
    }
    for (; ja < cA; ja += 4) {
      int jj = ja + eg;
      int s2 = __shfl(svA, jj);
      if (jj < cA) {
        uint4 u = *(const uint4*)(in + (size_t)s2 * 64 + sub * 4);
        add8(accA, u);
      }
    }
    // finish B
    int jb = j;
    for (; jb + 16 <= cB; jb += 16) {
      int b0 = __shfl(svB, jb + eg), b1 = __shfl(svB, jb + 4 + eg);
      int b2 = __shfl(svB, jb + 8 + eg), b3 = __shfl(svB, jb + 12 + eg);
      uint4 u0 = *(const uint4*)(in + (size_t)b0 * 64 + sub * 4);
      uint4 u1 = *(const uint4*)(in + (size_t)b1 * 64 + sub * 4);
      uint4 u2 = *(const uint4*)(in + (size_t)b2 * 64 + sub * 4);
      uint4 u3 = *(const uint4*)(in + (size_t)b3 * 64 + sub * 4);
      add8(accB, u0); add8(accB, u1); add8(accB, u2); add8(accB, u3);
    }
    for (; jb + 8 <= cB; jb += 8) {
      int b0 = __shfl(svB, jb + eg), b1 = __shfl(svB, jb + 4 + eg);
      uint4 u0 = *(const uint4*)(in + (size_t)b0 * 64 + sub * 4);
      uint4 u1 = *(const uint4*)(in + (size_t)b1 * 64 + sub * 4);
      add8(accB, u0); add8(accB, u1);
    }
    for (; jb < cB; jb += 4) {
      int jj = jb + eg;
      int s2 = __shfl(svB, jj);
      if (jj < cB) {
        uint4 u = *(const uint4*)(in + (size_t)s2 * 64 + sub * 4);
        add8(accB, u);
      }
    }
  }

#pragma unroll
  for (int k = 0; k < 8; ++k) {
    accA[k] += __shfl_down(accA[k], 32);
    accA[k] += __shfl_down(accA[k], 16);
    accB[k] += __shfl_down(accB[k], 32);
    accB[k] += __shfl_down(accB[k], 16);
  }
  if (eg == 0) {
    if (vA) {
      float sc = 1.0f / (float)max(dga, 1);
      uint4 o;
      o.x = (unsigned)f2bf(accA[0] * sc) | ((unsigned)f2bf(accA[1] * sc) << 16);
      o.y = (unsigned)f2bf(accA[2] * sc) | ((unsigned)f2bf(accA[3] * sc) << 16);
      o.z = (unsigned)f2bf(accA[4] * sc) | ((unsigned)f2bf(accA[5] * sc) << 16);
      o.w = (unsigned)f2bf(accA[6] * sc) | ((unsigned)f2bf(accA[7] * sc) << 16);
      *(uint4*)(mean + (size_t)nA * 64 + sub * 4) = o;
    }
    if (vB) {
      float sc = 1.0f / (float)max(dgb, 1);
      uint4 o;
      o.x = (unsigned)f2bf(accB[0] * sc) | ((unsigned)f2bf(accB[1] * sc) << 16);
      o.y = (unsigned)f2bf(accB[2] * sc) | ((unsigned)f2bf(accB[3] * sc) << 16);
      o.z = (unsigned)f2bf(accB[4] * sc) | ((unsigned)f2bf(accB[5] * sc) << 16);
      o.w = (unsigned)f2bf(accB[6] * sc) | ((unsigned)f2bf(accB[7] * sc) << 16);
      *(uint4*)(mean + (size_t)nB * 64 + sub * 4) = o;
    }
  }
}

// ---------------- MFMA GEMM: out = self@Wr.T + mean@Wl.T + b (layers 1-2) ----------------
template <int H, bool RELU, bool BF16OUT>
__global__ __launch_bounds__(256) void k_gemm(
    const unsigned short* __restrict__ selfB, const unsigned short* __restrict__ meanB,
    const unsigned short* __restrict__ Wb, const float* __restrict__ bias,
    void* __restrict__ outp, int n) {
  constexpr int TN = H / 32;
  int lane = threadIdx.x & 63;
  int w = threadIdx.x >> 6;
  int wr = w & 1, wc = w >> 1;
  int nodeBase = blockIdx.x * 128 + wr * 64;
  int colBase = wc * (H / 2);
  int l15 = lane & 15, quad = lane >> 4;

  f32x4 acc[4][TN];
#pragma unroll
  for (int t = 0; t < 4; ++t)
#pragma unroll
    for (int j = 0; j < TN; ++j) acc[t][j] = (f32x4){0.f, 0.f, 0.f, 0.f};

#pragma unroll
  for (int c = 0; c < 8; ++c) {
    const unsigned short* A = (c < 4) ? selfB : meanB;
    int ko = (c & 3) * 32 + quad * 8;
    short8 af[4], bfr[TN];
#pragma unroll
    for (int t = 0; t < 4; ++t) {
      int row = min(nodeBase + t * 16 + l15, n - 1);
      af[t] = *(const short8*)(A + (size_t)row * 128 + ko);
    }
#pragma unroll
    for (int j = 0; j < TN; ++j) {
      int cn = colBase + j * 16 + l15;
      bfr[j] = *(const short8*)(Wb + (size_t)cn * 256 + c * 32 + quad * 8);
    }
#pragma unroll
    for (int t = 0; t < 4; ++t)
#pragma unroll
      for (int j = 0; j < TN; ++j)
        acc[t][j] = __builtin_amdgcn_mfma_f32_16x16x32_bf16(af[t], bfr[j], acc[t][j], 0, 0, 0);
  }

#pragma unroll
  for (int j = 0; j < TN; ++j) {
    int col = colBase + j * 16 + l15;
    float bv = bias[col];
#pragma unroll
    for (int t = 0; t < 4; ++t) {
#pragma unroll
      for (int r = 0; r < 4; ++r) {
        int row = nodeBase + t * 16 + quad * 4 + r;
        if (row < n) {
          float v = acc[t][j][r] + bv;
          if (RELU) v = fmaxf(v, 0.f);
          if (BF16OUT) ((unsigned short*)outp)[(size_t)row * H + col] = f2bf(v);
          else ((float*)outp)[(size_t)row * H + col] = v;
        }
      }
    }
  }
}

// ---------------- layer-3 combined transform: out = h2@W3r.T + b3 (fp32); y3 = h2@W3l.T (bf16) ----------------
__global__ __launch_bounds__(256) void k_gemm3_both(
    const unsigned short* __restrict__ A,    // h2 [n][128]
    const unsigned short* __restrict__ Wb3,  // [64][256]: self half +0, mean half +128
    const float* __restrict__ bias,
    float* __restrict__ outp, unsigned short* __restrict__ y3, int n) {
  int lane = threadIdx.x & 63;
  int w = threadIdx.x >> 6;
  int wr = w & 1, wc = w >> 1;
  int nodeBase = blockIdx.x * 128 + wr * 64;
  int l15 = lane & 15, quad = lane >> 4;
  int woff = wc ? 128 : 0;
  f32x4 acc[4][4];
#pragma unroll
  for (int t = 0; t < 4; ++t)
#pragma unroll
    for (int j = 0; j < 4; ++j) acc[t][j] = (f32x4){0.f, 0.f, 0.f, 0.f};
#pragma unroll
  for (int c = 0; c < 4; ++c) {
    int ko = c * 32 + quad * 8;
    short8 af[4], bfr[4];
#pragma unroll
    for (int t = 0; t < 4; ++t) {
      int row = min(nodeBase + t * 16 + l15, n - 1);
      af[t] = *(const short8*)(A + (size_t)row * 128 + ko);
    }
#pragma unroll
    for (int j = 0; j < 4; ++j) {
      int cn = j * 16 + l15;
      bfr[j] = *(const short8*)(Wb3 + (size_t)cn * 256 + woff + c * 32 + quad * 8);
    }
#pragma unroll
    for (int t = 0; t < 4; ++t)
#pragma unroll
      for (int j = 0; j < 4; ++j)
        acc[t][j] = __builtin_amdgcn_mfma_f32_16x16x32_bf16(af[t], bfr[j], acc[t][j], 0, 0, 0);
  }
#pragma unroll
  for (int j = 0; j < 4; ++j) {
    int col = j * 16 + l15;
    float bv = wc ? 0.f : bias[col];
#pragma unroll
    for (int t = 0; t < 4; ++t) {
#pragma unroll
      for (int r = 0; r < 4; ++r) {
        int row = nodeBase + t * 16 + quad * 4 + r;
        if (row < n) {
          float v = acc[t][j][r] + bv;
          if (wc) y3[(size_t)row * 64 + col] = f2bf(v);
          else outp[(size_t)row * 64 + col] = v;
        }
      }
    }
  }
}

// ---------------- layer-3 aggregate: out += mean(y3 over in-neighbors) ----------------
// 2 nodes/wave (degree-matched). y3 rows 128B. Lane = (eg in [0,8)) x (sub in [0,8)).
__global__ void k_agg64_add(const unsigned* __restrict__ y3, const int* __restrict__ rowStart,
                            const int* __restrict__ deg, const int* __restrict__ srcs,
                            const int* __restrict__ perm, float* __restrict__ outp, int n) {
  int lane = threadIdx.x & 63;
  int w = threadIdx.x >> 6;
  int i0 = blockIdx.x * 8 + w * 2;
  bool vA = i0 < n, vB = i0 + 1 < n;
  int nA = vA ? perm[i0] : 0;
  int nB = vB ? perm[i0 + 1] : 0;
  int dga = vA ? deg[nA] : 0;
  int dgb = vB ? deg[nB] : 0;
  int r0a = vA ? rowStart[nA] : 0;
  int r0b = vB ? rowStart[nB] : 0;
  int sub = lane & 7;
  int eg = lane >> 3;
  float accA[8], accB[8];
#pragma unroll
  for (int k = 0; k < 8; ++k) { accA[k] = 0.f; accB[k] = 0.f; }

  int mx = max(dga, dgb);
  for (int base = 0; base < mx; base += 64) {
    int cA = min(64, dga - base);
    int cB = min(64, dgb - base);
    int svA = (lane < cA) ? srcs[r0a + base + lane] : 0;
    int svB = (lane < cB) ? srcs[r0b + base + lane] : 0;
    int j = 0;
    int cM = min(cA, cB);
    for (; j + 16 <= cM; j += 16) {
      int a0 = __shfl(svA, j + eg), a1 = __shfl(svA, j + 8 + eg);
      int b0 = __shfl(svB, j + eg), b1 = __shfl(svB, j + 8 + eg);
      uint4 uA0 = *(const uint4*)(y3 + (size_t)a0 * 32 + sub * 4);
      uint4 uA1 = *(const uint4*)(y3 + (size_t)a1 * 32 + sub * 4);
      uint4 uB0 = *(const uint4*)(y3 + (size_t)b0 * 32 + sub * 4);
      uint4 uB1 = *(const uint4*)(y3 + (size_t)b1 * 32 + sub * 4);
      add8(accA, uA0); add8(accA, uA1);
      add8(accB, uB0); add8(accB, uB1);
    }
    int ja = j;
    for (; ja + 16 <= cA; ja += 16) {
      int a0 = __shfl(svA, ja + eg), a1 = __shfl(svA, ja + 8 + eg);
      uint4 u0 = *(const uint4*)(y3 + (size_t)a0 * 32 + sub * 4);
      uint4 u1 = *(const uint4*)(y3 + (size_t)a1 * 32 + sub * 4);
      add8(accA, u0); add8(accA, u1);
    }
    for (; ja < cA; ja += 8) {
      int jj = ja + eg;
      int s2 = __shfl(svA, jj);
      if (jj < cA) {
        uint4 u = *(const uint4*)(y3 + (size_t)s2 * 32 + sub * 4);
        add8(accA, u);
      }
    }
    int jb = j;
    for (; jb + 16 <= cB; jb += 16) {
      int b0 = __shfl(svB, jb + eg), b1 = __shfl(svB, jb + 8 + eg);
      uint4 u0 = *(const uint4*)(y3 + (size_t)b0 * 32 + sub * 4);
      uint4 u1 = *(const uint4*)(y3 + (size_t)b1 * 32 + sub * 4);
      add8(accB, u0); add8(accB, u1);
    }
    for (; jb < cB; jb += 8) {
      int jj = jb + eg;
      int s2 = __shfl(svB, jj);
      if (jj < cB) {
        uint4 u = *(const uint4*)(y3 + (size_t)s2 * 32 + sub * 4);
        add8(accB, u);
      }
    }
  }

#pragma unroll
  for (int k = 0; k < 8; ++k) {
    accA[k] += __shfl_down(accA[k], 32);
    accA[k] += __shfl_down(accA[k], 16);
    accA[k] += __shfl_down(accA[k], 8);
    accB[k] += __shfl_down(accB[k], 32);
    accB[k] += __shfl_down(accB[k], 16);
    accB[k] += __shfl_down(accB[k], 8);
  }
  if (eg == 0) {
    if (vA && dga > 0) {
      float sc = 1.0f / (float)dga;
      float* op = outp + (size_t)nA * 64 + sub * 8;
      float4 a = *(float4*)op;
      float4 b = *(float4*)(op + 4);
      a.x += accA[0] * sc; a.y += accA[1] * sc; a.z += accA[2] * sc; a.w += accA[3] * sc;
      b.x += accA[4] * sc; b.y += accA[5] * sc; b.z += accA[6] * sc; b.w += accA[7] * sc;
      *(float4*)op = a;
      *(float4*)(op + 4) = b;
    }
    if (vB && dgb > 0) {
      float sc = 1.0f / (float)dgb;
      float* op = outp + (size_t)nB * 64 + sub * 8;
      float4 a = *(float4*)op;
      float4 b = *(float4*)(op + 4);
      a.x += accB[0] * sc; a.y += accB[1] * sc; a.z += accB[2] * sc; a.w += accB[3] * sc;
      b.x += accB[4] * sc; b.y += accB[5] * sc; b.z += accB[6] * sc; b.w += accB[7] * sc;
      *(float4*)op = a;
      *(float4*)(op + 4) = b;
    }
  }
}

// ---------------- launch ----------------

extern "C" void kernel_launch(void* const* d_in, const int* in_sizes, int n_in,
                              void* d_out, int out_size, void* d_ws, size_t ws_size,
                              hipStream_t stream) {
  (void)n_in; (void)out_size; (void)ws_size;
  const float* x = (const float*)d_in[0];
  const void* edges = d_in[1];
  const float* W1l = (const float*)d_in[2];
  const float* W1r = (const float*)d_in[3];
  const float* b1 = (const float*)d_in[4];
  const float* W2l = (const float*)d_in[5];
  const float* W2r = (const float*)d_in[6];
  const float* b2 = (const float*)d_in[7];
  const float* W3l = (const float*)d_in[8];
  const float* W3r = (const float*)d_in[9];
  const float* b3 = (const float*)d_in[10];
  float* out = (float*)d_out;

  const int N = in_sizes[0] / 128;
  const int E = in_sizes[1] / 2;
  const int NB = (N + BSIZE - 1) >> BSHIFT;

  char* ws = (char*)d_ws;
  size_t off = 0;
  auto alloc = [&](size_t bytes) -> char* {
    char* p = ws + off;
    off = (off + bytes + 255) & ~(size_t)255;
    return p;
  };
  int* bucketCursor = (int*)alloc((size_t)NB * 4);
  unsigned* bucketed = (unsigned*)alloc((size_t)NB * CAP * 4);
  int* rowStart = (int*)alloc((size_t)N * 4);
  int* deg = (int*)alloc((size_t)N * 4);
  int* perm = (int*)alloc((size_t)N * 4);
  int* srcSorted = (int*)alloc((size_t)NB * CAP * 4);
  unsigned short* xb = (unsigned short*)alloc((size_t)N * 128 * 2);
  unsigned short* mean = (unsigned short*)alloc((size_t)N * 128 * 2);
  unsigned short* h1 = (unsigned short*)alloc((size_t)N * 128 * 2);
  unsigned short* h2 = (unsigned short*)alloc((size_t)N * 128 * 2);
  unsigned short* y3 = (unsigned short*)alloc((size_t)N * 64 * 2);
  unsigned short* Wb1 = (unsigned short*)alloc(128 * 256 * 2);
  unsigned short* Wb2 = (unsigned short*)alloc(128 * 256 * 2);
  unsigned short* Wb3 = (unsigned short*)alloc(64 * 256 * 2);

  int gCast = NBLK(N * 64, 256) + 320;
  int gE = NBLK(E, ECHUNK);
  int gAgg = NBLK(N, 8);
  int gGemm = NBLK(N, 128);

  hipMemsetAsync(bucketCursor, 0, (size_t)NB * 4, stream);
  k_cast<<<gCast, 256, 0, stream>>>(x, (unsigned*)xb, N,
                                    W1l, W1r, Wb1, W2l, W2r, Wb2, W3l, W3r, Wb3);
  k_scatter<<<gE, 256, 0, stream>>>(edges, bucketCursor, bucketed, E, NB);
  k_csr<<<NB, 256, 0, stream>>>(bucketed, bucketCursor, rowStart, deg, srcSorted, perm, N, NB);

  // layer 1
  k_aggregate<<<gAgg, 256, 0, stream>>>((const unsigned*)xb, rowStart, deg, srcSorted, perm,
                                        (unsigned*)mean, N);
  k_gemm<128, true, true><<<gGemm, 256, 0, stream>>>(xb, mean, Wb1, b1, h1, N);
  // layer 2
  k_aggregate<<<gAgg, 256, 0, stream>>>((const unsigned*)h1, rowStart, deg, srcSorted, perm,
                                        (unsigned*)mean, N);
  k_gemm<128, true, true><<<gGemm, 256, 0, stream>>>(h1, mean, Wb2, b2, h2, N);
  // layer 3: transform-first
  k_gemm3_both<<<gGemm, 256, 0, stream>>>(h2, Wb3, b3, out, y3, N);
  k_agg64_add<<<gAgg, 256, 0, stream>>>((const unsigned*)y3, rowStart, deg, srcSorted, perm,
                                        out, N);
}